// Round 9
// baseline (755.237 us; speedup 1.0000x reference)
//
#include <hip/hip_runtime.h>

#define N_NODES 10242
#define NNZ_E   71694
#define NNZ_PAD_MAX (NNZ_E + 3 * N_NODES)   // rows padded to multiple of 4
#define BT      32      // B*T
#define C_IN    16
#define K_S     20
#define C_OUT   32
#define F       512     // BT * C_IN
typedef unsigned short u16;
typedef unsigned int   u32;

#define BUF_FLOATS ((size_t)N_NODES * F)    // fp32 T buffer, layout [n][bt*16+c]
#define BUF_BYTES  (BUF_FLOATS * 4)         // ~21 MB
#define PROJ_ELEMS ((size_t)N_NODES * F)    // bf16 proj copy, layout [n][bt*16+c]
#define PROJ_BYTES (PROJ_ELEMS * 2)         // ~10.5 MB
#define RBF_TARGET 8                        // proj ring slots: keep total footprint < L3

typedef __attribute__((ext_vector_type(8)))  short short8;
typedef __attribute__((ext_vector_type(16))) float float16;

__device__ __forceinline__ u16 f2bf(float f) {
    union { float f; u32 u; } v; v.f = f;
    u32 r = v.u + 0x7fffu + ((v.u >> 16) & 1u);   // RNE
    return (u16)(r >> 16);
}

// ---------------- CSR build (deterministic, rows padded to x4) -------------

__global__ void zero_kernel(int* p, int n) {
    int i = blockIdx.x * blockDim.x + threadIdx.x;
    if (i < n) p[i] = 0;
}

__global__ void count_kernel(const int* __restrict__ erow, int* cnt) {
    int e = blockIdx.x * blockDim.x + threadIdx.x;
    if (e < NNZ_E) atomicAdd(&cnt[erow[e]], 1);
}

__global__ void scan_kernel(const int* __restrict__ cnt, int* row_ptr, int* cursor) {
    const int T = 256;
    const int chunk = (N_NODES + T - 1) / T;  // 41
    __shared__ int part[T];
    int t = threadIdx.x;
    int base = t * chunk;
    int s = 0;
    for (int i = 0; i < chunk; ++i) {
        int idx = base + i;
        if (idx < N_NODES) s += (cnt[idx] + 3) & ~3;
    }
    part[t] = s;
    __syncthreads();
    for (int off = 1; off < T; off <<= 1) {
        int v = (t >= off) ? part[t - off] : 0;
        __syncthreads();
        part[t] += v;
        __syncthreads();
    }
    int run = (t == 0) ? 0 : part[t - 1];
    for (int i = 0; i < chunk; ++i) {
        int idx = base + i;
        if (idx < N_NODES) {
            row_ptr[idx] = run;
            cursor[idx]  = run;
            run += (cnt[idx] + 3) & ~3;
        }
    }
    if (base <= N_NODES && N_NODES < base + chunk) {
        row_ptr[N_NODES] = run;
    }
}

__global__ void scatter_kernel(const int* __restrict__ erow, int* cursor, int* __restrict__ eidx) {
    int e = blockIdx.x * blockDim.x + threadIdx.x;
    if (e < NNZ_E) {
        int p = atomicAdd(&cursor[erow[e]], 1);
        eidx[p] = e;
    }
}

__global__ void sort_rows_kernel(const int* __restrict__ row_ptr, const int* __restrict__ cnt,
                                 int* eidx) {
    int r = blockIdx.x * blockDim.x + threadIdx.x;
    if (r >= N_NODES) return;
    int s = row_ptr[r], e = s + cnt[r];
    for (int i = s + 1; i < e; ++i) {
        int key = eidx[i];
        int j = i - 1;
        while (j >= s && eidx[j] > key) { eidx[j + 1] = eidx[j]; --j; }
        eidx[j + 1] = key;
    }
}

__global__ void fill_csr_kernel(const int* __restrict__ row_ptr, const int* __restrict__ cnt,
                                const int* __restrict__ eidx,
                                const int* __restrict__ ecol, const float* __restrict__ eval,
                                int2* __restrict__ cpack) {
    int r = blockIdx.x * blockDim.x + threadIdx.x;
    if (r >= N_NODES) return;
    int s = row_ptr[r], e = s + cnt[r];
    for (int p = s; p < e; ++p) {
        int ed = eidx[p];
        cpack[p] = make_int2(ecol[ed], __float_as_int(eval[ed]));
    }
}

// B-fragments for v_mfma_f32_32x32x16_bf16 (verified layout, round 6):
// lane L, reg j -> B[k=8*(L>>5)+j][col=L&31] = W[cout=col][c=k][k_cheb]
__global__ void wtfrag_kernel(const float* __restrict__ W, u16* __restrict__ wtfrag) {
    int i = blockIdx.x * blockDim.x + threadIdx.x;  // K_S*64*8 = 10240
    if (i >= K_S * 64 * 8) return;
    int j    = i & 7;
    int lane = (i >> 3) & 63;
    int k    = i >> 9;
    int cout = lane & 31;
    int c    = ((lane >> 5) << 3) + j;
    wtfrag[i] = f2bf(W[cout * (C_IN * K_S) + c * K_S + k]);
}

// ---------------- transform: x -> T0 (fp32) + bf16 proj copy --------------

__global__ __launch_bounds__(256) void transform_kernel(
        const float* __restrict__ x, float* __restrict__ T0, u16* __restrict__ proj0) {
    int g = blockIdx.x * 256 + threadIdx.x;   // over N*F
    int n   = g >> 9;
    int rem = g & 511;
    int bt  = rem >> 4;
    int c   = rem & 15;
    float v = x[((size_t)bt * N_NODES + n) * C_IN + c];
    T0[(size_t)n * F + rem] = v;
    proj0[(size_t)n * F + rem] = f2bf(v);
}

// ---------------- Chebyshev step: wave-per-node, 4-edge batches ------------
// dst = alpha * L @ srcB + beta * srcA ; projw = bf16(dst)

__global__ __launch_bounds__(64) void spmm_step_kernel(
        const float* __restrict__ srcB, const float* __restrict__ srcA,
        float* __restrict__ dst, u16* __restrict__ projw,
        const int* __restrict__ row_ptr, const int2* __restrict__ cpack,
        float alpha, float beta) {
    int n = blockIdx.x;                   // block-uniform -> scalar loads
    int lane = threadIdx.x;
    int s = row_ptr[n], e_end = row_ptr[n + 1];   // padded count, multiple of 4
    int o1 = lane * 4;                    // first half of the 512-float row
    int o2 = 256 + lane * 4;              // second half

    // hoist srcA load ahead of the gather loop (independent; overlaps)
    float4 sa = make_float4(0.f, 0.f, 0.f, 0.f);
    float4 sb = make_float4(0.f, 0.f, 0.f, 0.f);
    if (beta != 0.f) {
        sa = *(const float4*)(srcA + (size_t)n * F + o1);
        sb = *(const float4*)(srcA + (size_t)n * F + o2);
    }

    float4 aa0 = {0,0,0,0}, ab0 = {0,0,0,0};
    float4 aa1 = {0,0,0,0}, ab1 = {0,0,0,0};

    for (int e = s; e < e_end; e += 4) {
        int2 p0 = cpack[e + 0], p1 = cpack[e + 1];
        int2 p2 = cpack[e + 2], p3 = cpack[e + 3];
        const float* r0 = srcB + (size_t)p0.x * F;
        const float* r1 = srcB + (size_t)p1.x * F;
        const float* r2 = srcB + (size_t)p2.x * F;
        const float* r3 = srcB + (size_t)p3.x * F;
        float4 b0a = *(const float4*)(r0 + o1), b0b = *(const float4*)(r0 + o2);
        float4 b1a = *(const float4*)(r1 + o1), b1b = *(const float4*)(r1 + o2);
        float4 b2a = *(const float4*)(r2 + o1), b2b = *(const float4*)(r2 + o2);
        float4 b3a = *(const float4*)(r3 + o1), b3b = *(const float4*)(r3 + o2);
        float v0 = __int_as_float(p0.y), v1 = __int_as_float(p1.y);
        float v2 = __int_as_float(p2.y), v3 = __int_as_float(p3.y);
        aa0.x += v0 * b0a.x; aa0.y += v0 * b0a.y; aa0.z += v0 * b0a.z; aa0.w += v0 * b0a.w;
        ab0.x += v0 * b0b.x; ab0.y += v0 * b0b.y; ab0.z += v0 * b0b.z; ab0.w += v0 * b0b.w;
        aa1.x += v1 * b1a.x; aa1.y += v1 * b1a.y; aa1.z += v1 * b1a.z; aa1.w += v1 * b1a.w;
        ab1.x += v1 * b1b.x; ab1.y += v1 * b1b.y; ab1.z += v1 * b1b.z; ab1.w += v1 * b1b.w;
        aa0.x += v2 * b2a.x; aa0.y += v2 * b2a.y; aa0.z += v2 * b2a.z; aa0.w += v2 * b2a.w;
        ab0.x += v2 * b2b.x; ab0.y += v2 * b2b.y; ab0.z += v2 * b2b.z; ab0.w += v2 * b2b.w;
        aa1.x += v3 * b3a.x; aa1.y += v3 * b3a.y; aa1.z += v3 * b3a.z; aa1.w += v3 * b3a.w;
        ab1.x += v3 * b3b.x; ab1.y += v3 * b3b.y; ab1.z += v3 * b3b.z; ab1.w += v3 * b3b.w;
    }

    float ya[4] = { alpha * (aa0.x + aa1.x) + beta * sa.x,
                    alpha * (aa0.y + aa1.y) + beta * sa.y,
                    alpha * (aa0.z + aa1.z) + beta * sa.z,
                    alpha * (aa0.w + aa1.w) + beta * sa.w };
    float yb[4] = { alpha * (ab0.x + ab1.x) + beta * sb.x,
                    alpha * (ab0.y + ab1.y) + beta * sb.y,
                    alpha * (ab0.z + ab1.z) + beta * sb.z,
                    alpha * (ab0.w + ab1.w) + beta * sb.w };

    *(float4*)(dst + (size_t)n * F + o1) = *(float4*)ya;
    *(float4*)(dst + (size_t)n * F + o2) = *(float4*)yb;

    u16* pw = projw + (size_t)n * F;
    uint2 pa, pb;
    pa.x = (u32)f2bf(ya[0]) | ((u32)f2bf(ya[1]) << 16);
    pa.y = (u32)f2bf(ya[2]) | ((u32)f2bf(ya[3]) << 16);
    pb.x = (u32)f2bf(yb[0]) | ((u32)f2bf(yb[1]) << 16);
    pb.y = (u32)f2bf(yb[2]) | ((u32)f2bf(yb[3]) << 16);
    *(uint2*)(pw + o1) = pa;
    *(uint2*)(pw + o2) = pb;
}

// ---------------- MFMA projection, prefetch-unrolled (kcnt <= 8) ----------
// All A/B fragments for the chunk loaded into registers up front (<=16
// independent loads in flight), then the MFMA chain consumes them.
// Layouts verified round 6.

__global__ __launch_bounds__(256) void proj_mfma_kernel(
        const u16* __restrict__ projbase, int Rbf, int k0, int kcnt,
        const u16* __restrict__ wtfrag, float* __restrict__ out, int accumulate) {
    int wave = threadIdx.x >> 6;
    int lane = threadIdx.x & 63;
    int n = blockIdx.x * 4 + wave;
    if (n >= N_NODES) return;

    int col = lane & 31;
    int grp = lane >> 5;
    size_t aoff = (size_t)n * F + (size_t)col * 16 + grp * 8;

    union { uint4 u; short8 s; } av[8], bv[8];
    #pragma unroll
    for (int j = 0; j < 8; ++j) {
        int jj = (j < kcnt) ? j : 0;      // clamp tail to a valid (hot) slot
        int k = k0 + jj;
        av[j].u = *(const uint4*)(projbase + (size_t)(k % Rbf) * PROJ_ELEMS + aoff);
        bv[j].u = *(const uint4*)(wtfrag + (size_t)k * 512 + lane * 8);
    }

    float16 acc = {};
    #pragma unroll
    for (int j = 0; j < 8; ++j) {
        if (j < kcnt)
            acc = __builtin_amdgcn_mfma_f32_32x32x16_bf16(av[j].s, bv[j].s, acc, 0, 0, 0);
    }

    #pragma unroll
    for (int r = 0; r < 16; ++r) {
        int bt = (r & 3) + 8 * (r >> 2) + 4 * grp;
        float* op = out + ((size_t)bt * N_NODES + n) * C_OUT + col;
        if (accumulate) *op += acc[r];
        else            *op  = acc[r];
    }
}

// ---------------- host launch ----------------

extern "C" void kernel_launch(void* const* d_in, const int* in_sizes, int n_in,
                              void* d_out, int out_size, void* d_ws, size_t ws_size,
                              hipStream_t stream) {
    const float* x    = (const float*)d_in[0];
    const int*   erow = (const int*)  d_in[1];
    const int*   ecol = (const int*)  d_in[2];
    const float* eval = (const float*)d_in[3];
    const float* W    = (const float*)d_in[4];
    float* out = (float*)d_out;

    char* ws = (char*)d_ws;
    size_t o = 0;
    auto alloc = [&](size_t bytes) -> char* {
        o = (o + 511) & ~(size_t)511;
        char* r = ws + o;
        o += bytes;
        return r;
    };
    int*   cnt     = (int*)  alloc((size_t)N_NODES * 4);
    int*   row_ptr = (int*)  alloc((size_t)(N_NODES + 1) * 4);
    int*   cursor  = (int*)  alloc((size_t)N_NODES * 4);
    int*   eidx    = (int*)  alloc((size_t)NNZ_PAD_MAX * 4);
    int2*  cpack   = (int2*) alloc((size_t)NNZ_PAD_MAX * 8);
    u16*   wtfrag  = (u16*)  alloc((size_t)K_S * 512 * 2);

    // fp32 recurrence ring: 3 buffers
    float* fbase = (float*)alloc(3 * BUF_BYTES);
    auto buf = [&](int k) -> float* { return fbase + (size_t)(k % 3) * BUF_FLOATS; };

    // bf16 proj ring: SMALL (Rbf=8) so the hot working set stays under the
    // 256 MB Infinity Cache: 63 (fp32 ring) + 84 (proj ring) + ~2 (CSR).
    o = (o + 511) & ~(size_t)511;
    size_t remain = (ws_size > o) ? (ws_size - o) : 0;
    int Rbf = (int)(remain / PROJ_BYTES);
    if (Rbf > RBF_TARGET) Rbf = RBF_TARGET;
    if (Rbf < 3) Rbf = 3;
    u16* projbase = (u16*)alloc((size_t)Rbf * PROJ_BYTES);
    auto projslot = [&](int k) -> u16* { return projbase + (size_t)(k % Rbf) * PROJ_ELEMS; };

    // CSR build (deterministic, padded to x4) + weight fragments
    zero_kernel<<<(N_NODES + 255) / 256, 256, 0, stream>>>(cnt, N_NODES);
    zero_kernel<<<(2 * NNZ_PAD_MAX + 255) / 256, 256, 0, stream>>>((int*)cpack, 2 * NNZ_PAD_MAX);
    count_kernel<<<(NNZ_E + 255) / 256, 256, 0, stream>>>(erow, cnt);
    scan_kernel<<<1, 256, 0, stream>>>(cnt, row_ptr, cursor);
    scatter_kernel<<<(NNZ_E + 255) / 256, 256, 0, stream>>>(erow, cursor, eidx);
    sort_rows_kernel<<<(N_NODES + 255) / 256, 256, 0, stream>>>(row_ptr, cnt, eidx);
    fill_csr_kernel<<<(N_NODES + 255) / 256, 256, 0, stream>>>(row_ptr, cnt, eidx, ecol, eval, cpack);
    wtfrag_kernel<<<(K_S * 512 + 255) / 256, 256, 0, stream>>>(W, wtfrag);

    const int proj_blocks = (N_NODES + 3) / 4;
    int c0 = 0;
    auto maybe_pass = [&](int k_done) {
        int target = K_S - c0;
        if (target > Rbf) target = Rbf;
        if (target > 8)   target = 8;     // proj kernel prefetch depth
        if (target > 0 && (k_done - c0 + 1) == target) {
            proj_mfma_kernel<<<proj_blocks, 256, 0, stream>>>(
                projbase, Rbf, c0, target, wtfrag, out, (c0 > 0) ? 1 : 0);
            c0 += target;
        }
    };

    // T0
    transform_kernel<<<(int)(BUF_FLOATS / 256), 256, 0, stream>>>(x, buf(0), projslot(0));
    maybe_pass(0);

    // T1 = L T0 ; Tk = 2 L T_{k-1} - T_{k-2}
    for (int k = 1; k < K_S; ++k) {
        const float* srcB = buf(k - 1);
        const float* srcA = (k >= 2) ? buf(k - 2) : buf(k - 1);  // unread when beta==0
        float alpha = (k == 1) ? 1.f : 2.f;
        float beta  = (k == 1) ? 0.f : -1.f;
        spmm_step_kernel<<<N_NODES, 64, 0, stream>>>(
            srcB, srcA, buf(k), projslot(k), row_ptr, cpack, alpha, beta);
        maybe_pass(k);
    }
}

// Round 10
// 491.396 us; speedup vs baseline: 1.5369x; 1.5369x over previous
//
#include <hip/hip_runtime.h>

#define N_NODES 10242
#define NNZ_E   71694
#define NNZ_PAD_MAX (NNZ_E + 3 * N_NODES)   // rows padded to multiple of 4
#define BT      32      // B*T
#define C_IN    16
#define K_S     20
#define C_OUT   32
#define F       512     // BT * C_IN
typedef unsigned short u16;
typedef unsigned int   u32;

#define RING_ELEMS ((size_t)N_NODES * F)    // f16 elems per ring slot, layout [n][bt*16+c]
#define RING_BYTES (RING_ELEMS * 2)         // ~10.5 MB
#define R_SLOTS    8                        // ring slots; chunk == R is safe (stream-ordered)

typedef __attribute__((ext_vector_type(8)))  _Float16 half8;
typedef __attribute__((ext_vector_type(16))) float    float16;

__device__ __forceinline__ void unpack8h(uint4 u, float* f) {
    union { uint4 u; _Float16 h[8]; } v; v.u = u;
    #pragma unroll
    for (int i = 0; i < 8; ++i) f[i] = (float)v.h[i];
}
__device__ __forceinline__ uint4 pack8h(const float* f) {
    union { uint4 u; _Float16 h[8]; } v;
    #pragma unroll
    for (int i = 0; i < 8; ++i) v.h[i] = (_Float16)f[i];
    return v.u;
}
__device__ __forceinline__ u16 f2h(float f) {
    union { _Float16 h; u16 u; } v; v.h = (_Float16)f; return v.u;
}

// ---------------- CSR build (deterministic, rows padded to x4) -------------

__global__ void zero_kernel(int* p, int n) {
    int i = blockIdx.x * blockDim.x + threadIdx.x;
    if (i < n) p[i] = 0;
}

__global__ void count_kernel(const int* __restrict__ erow, int* cnt) {
    int e = blockIdx.x * blockDim.x + threadIdx.x;
    if (e < NNZ_E) atomicAdd(&cnt[erow[e]], 1);
}

__global__ void scan_kernel(const int* __restrict__ cnt, int* row_ptr, int* cursor) {
    const int T = 256;
    const int chunk = (N_NODES + T - 1) / T;  // 41
    __shared__ int part[T];
    int t = threadIdx.x;
    int base = t * chunk;
    int s = 0;
    for (int i = 0; i < chunk; ++i) {
        int idx = base + i;
        if (idx < N_NODES) s += (cnt[idx] + 3) & ~3;
    }
    part[t] = s;
    __syncthreads();
    for (int off = 1; off < T; off <<= 1) {
        int v = (t >= off) ? part[t - off] : 0;
        __syncthreads();
        part[t] += v;
        __syncthreads();
    }
    int run = (t == 0) ? 0 : part[t - 1];
    for (int i = 0; i < chunk; ++i) {
        int idx = base + i;
        if (idx < N_NODES) {
            row_ptr[idx] = run;
            cursor[idx]  = run;
            run += (cnt[idx] + 3) & ~3;
        }
    }
    if (base <= N_NODES && N_NODES < base + chunk) {
        row_ptr[N_NODES] = run;
    }
}

__global__ void scatter_kernel(const int* __restrict__ erow, int* cursor, int* __restrict__ eidx) {
    int e = blockIdx.x * blockDim.x + threadIdx.x;
    if (e < NNZ_E) {
        int p = atomicAdd(&cursor[erow[e]], 1);
        eidx[p] = e;
    }
}

__global__ void sort_rows_kernel(const int* __restrict__ row_ptr, const int* __restrict__ cnt,
                                 int* eidx) {
    int r = blockIdx.x * blockDim.x + threadIdx.x;
    if (r >= N_NODES) return;
    int s = row_ptr[r], e = s + cnt[r];
    for (int i = s + 1; i < e; ++i) {
        int key = eidx[i];
        int j = i - 1;
        while (j >= s && eidx[j] > key) { eidx[j + 1] = eidx[j]; --j; }
        eidx[j + 1] = key;
    }
}

__global__ void fill_csr_kernel(const int* __restrict__ row_ptr, const int* __restrict__ cnt,
                                const int* __restrict__ eidx,
                                const int* __restrict__ ecol, const float* __restrict__ eval,
                                int2* __restrict__ cpack) {
    int r = blockIdx.x * blockDim.x + threadIdx.x;
    if (r >= N_NODES) return;
    int s = row_ptr[r], e = s + cnt[r];
    for (int p = s; p < e; ++p) {
        int ed = eidx[p];
        cpack[p] = make_int2(ecol[ed], __float_as_int(eval[ed]));
    }
}

// B-fragments for v_mfma_f32_32x32x16_f16 (same layout as verified bf16 path):
// lane L, reg j -> B[k=8*(L>>5)+j][col=L&31] = W[cout=col][c=k][k_cheb]
__global__ void wtfrag_kernel(const float* __restrict__ W, u16* __restrict__ wtfrag) {
    int i = blockIdx.x * blockDim.x + threadIdx.x;  // K_S*64*8 = 10240
    if (i >= K_S * 64 * 8) return;
    int j    = i & 7;
    int lane = (i >> 3) & 63;
    int k    = i >> 9;
    int cout = lane & 31;
    int c    = ((lane >> 5) << 3) + j;
    wtfrag[i] = f2h(W[cout * (C_IN * K_S) + c * K_S + k]);
}

// ---------------- transform: x (fp32) -> ring slot 0 (f16) ----------------
// ring layout: T[n][bt*16 + c]

__global__ __launch_bounds__(256) void transform_kernel(
        const float* __restrict__ x, u16* __restrict__ T0) {
    int g = blockIdx.x * 256 + threadIdx.x;   // over N*F
    int n   = g >> 9;
    int rem = g & 511;
    int bt  = rem >> 4;
    int c   = rem & 15;
    float v = x[((size_t)bt * N_NODES + n) * C_IN + c];
    T0[(size_t)n * F + rem] = f2h(v);
}

// ---------------- Chebyshev step: wave-per-node, f16 ring, fp32 math -------
// dst = alpha * L @ srcB + beta * srcA   (all ring slots f16)

__global__ __launch_bounds__(64) void spmm_step_kernel(
        const u16* __restrict__ srcB, const u16* __restrict__ srcA,
        u16* __restrict__ dst,
        const int* __restrict__ row_ptr, const int2* __restrict__ cpack,
        float alpha, float beta) {
    int n = blockIdx.x;                   // block-uniform -> scalar loads
    int lane = threadIdx.x;
    int s = row_ptr[n], e_end = row_ptr[n + 1];   // padded count, multiple of 4

    // hoist srcA load (independent; overlaps gather)
    float a[8] = {0,0,0,0,0,0,0,0};
    if (beta != 0.f) {
        uint4 ua = ((const uint4*)(srcA + (size_t)n * F))[lane];
        unpack8h(ua, a);
    }

    float acc0[8] = {0,0,0,0,0,0,0,0};
    float acc1[8] = {0,0,0,0,0,0,0,0};

    for (int e = s; e < e_end; e += 4) {
        int2 p0 = cpack[e + 0], p1 = cpack[e + 1];
        int2 p2 = cpack[e + 2], p3 = cpack[e + 3];
        uint4 g0 = ((const uint4*)(srcB + (size_t)p0.x * F))[lane];
        uint4 g1 = ((const uint4*)(srcB + (size_t)p1.x * F))[lane];
        uint4 g2 = ((const uint4*)(srcB + (size_t)p2.x * F))[lane];
        uint4 g3 = ((const uint4*)(srcB + (size_t)p3.x * F))[lane];
        float b0[8], b1[8], b2[8], b3[8];
        unpack8h(g0, b0); unpack8h(g1, b1); unpack8h(g2, b2); unpack8h(g3, b3);
        float v0 = __int_as_float(p0.y), v1 = __int_as_float(p1.y);
        float v2 = __int_as_float(p2.y), v3 = __int_as_float(p3.y);
        #pragma unroll
        for (int i = 0; i < 8; ++i) {
            acc0[i] += v0 * b0[i];
            acc1[i] += v1 * b1[i];
            acc0[i] += v2 * b2[i];
            acc1[i] += v3 * b3[i];
        }
    }

    float y[8];
    #pragma unroll
    for (int i = 0; i < 8; ++i)
        y[i] = alpha * (acc0[i] + acc1[i]) + beta * a[i];

    ((uint4*)(dst + (size_t)n * F))[lane] = pack8h(y);
}

// ---------------- MFMA projection over a chunk (kcnt <= 8), f16 -----------
// per wave: one node; tile M=32(bt) x N=32(cout), K=kcnt*16.
// A: m=L&31, kk=8*(L>>5)+j ; C/D: col=L&31, row=(reg&3)+8*(reg>>2)+4*(L>>5)
// (layouts verified round 6; C/D layout dtype-independent)

__global__ __launch_bounds__(256) void proj_mfma_kernel(
        const u16* __restrict__ ring, int k0, int kcnt,
        const u16* __restrict__ wtfrag, float* __restrict__ out, int accumulate) {
    int wave = threadIdx.x >> 6;
    int lane = threadIdx.x & 63;
    int n = blockIdx.x * 4 + wave;
    if (n >= N_NODES) return;

    int col = lane & 31;
    int grp = lane >> 5;
    size_t aoff = (size_t)n * F + (size_t)col * 16 + grp * 8;

    union { uint4 u; half8 h; } av[8], bv[8];
    #pragma unroll
    for (int j = 0; j < 8; ++j) {
        int jj = (j < kcnt) ? j : 0;      // clamp tail to a valid (hot) slot
        int k = k0 + jj;
        av[j].u = *(const uint4*)(ring + (size_t)(k % R_SLOTS) * RING_ELEMS + aoff);
        bv[j].u = *(const uint4*)(wtfrag + (size_t)k * 512 + lane * 8);
    }

    float16 acc = {};
    #pragma unroll
    for (int j = 0; j < 8; ++j) {
        if (j < kcnt)
            acc = __builtin_amdgcn_mfma_f32_32x32x16_f16(av[j].h, bv[j].h, acc, 0, 0, 0);
    }

    #pragma unroll
    for (int r = 0; r < 16; ++r) {
        int bt = (r & 3) + 8 * (r >> 2) + 4 * grp;
        float* op = out + ((size_t)bt * N_NODES + n) * C_OUT + col;
        if (accumulate) *op += acc[r];
        else            *op  = acc[r];
    }
}

// ---------------- host launch ----------------

extern "C" void kernel_launch(void* const* d_in, const int* in_sizes, int n_in,
                              void* d_out, int out_size, void* d_ws, size_t ws_size,
                              hipStream_t stream) {
    const float* x    = (const float*)d_in[0];
    const int*   erow = (const int*)  d_in[1];
    const int*   ecol = (const int*)  d_in[2];
    const float* eval = (const float*)d_in[3];
    const float* W    = (const float*)d_in[4];
    float* out = (float*)d_out;

    char* ws = (char*)d_ws;
    size_t o = 0;
    auto alloc = [&](size_t bytes) -> char* {
        o = (o + 511) & ~(size_t)511;
        char* r = ws + o;
        o += bytes;
        return r;
    };
    int*   cnt     = (int*)  alloc((size_t)N_NODES * 4);
    int*   row_ptr = (int*)  alloc((size_t)(N_NODES + 1) * 4);
    int*   cursor  = (int*)  alloc((size_t)N_NODES * 4);
    int*   eidx    = (int*)  alloc((size_t)NNZ_PAD_MAX * 4);
    int2*  cpack   = (int2*) alloc((size_t)NNZ_PAD_MAX * 8);
    u16*   wtfrag  = (u16*)  alloc((size_t)K_S * 512 * 2);

    // f16 T ring: R_SLOTS slots (~84 MB); also the proj input — no side copy
    u16* ring = (u16*)alloc((size_t)R_SLOTS * RING_BYTES);
    auto slot = [&](int k) -> u16* { return ring + (size_t)(k % R_SLOTS) * RING_ELEMS; };

    // CSR build (deterministic, padded to x4) + weight fragments
    zero_kernel<<<(N_NODES + 255) / 256, 256, 0, stream>>>(cnt, N_NODES);
    zero_kernel<<<(2 * NNZ_PAD_MAX + 255) / 256, 256, 0, stream>>>((int*)cpack, 2 * NNZ_PAD_MAX);
    count_kernel<<<(NNZ_E + 255) / 256, 256, 0, stream>>>(erow, cnt);
    scan_kernel<<<1, 256, 0, stream>>>(cnt, row_ptr, cursor);
    scatter_kernel<<<(NNZ_E + 255) / 256, 256, 0, stream>>>(erow, cursor, eidx);
    sort_rows_kernel<<<(N_NODES + 255) / 256, 256, 0, stream>>>(row_ptr, cnt, eidx);
    fill_csr_kernel<<<(N_NODES + 255) / 256, 256, 0, stream>>>(row_ptr, cnt, eidx, ecol, eval, cpack);
    wtfrag_kernel<<<(K_S * 512 + 255) / 256, 256, 0, stream>>>(W, wtfrag);

    const int proj_blocks = (N_NODES + 3) / 4;
    int c0 = 0;
    auto maybe_pass = [&](int k_done) {
        int target = K_S - c0;
        if (target > R_SLOTS) target = R_SLOTS;   // chunk == R safe (stream-ordered)
        if (target > 0 && (k_done - c0 + 1) == target) {
            proj_mfma_kernel<<<proj_blocks, 256, 0, stream>>>(
                ring, c0, target, wtfrag, out, (c0 > 0) ? 1 : 0);
            c0 += target;
        }
    };

    // T0 -> slot 0
    transform_kernel<<<(int)(RING_ELEMS / 256), 256, 0, stream>>>(x, slot(0));
    maybe_pass(0);

    // T1 = L T0 ; Tk = 2 L T_{k-1} - T_{k-2}
    for (int k = 1; k < K_S; ++k) {
        const u16* srcB = slot(k - 1);
        const u16* srcA = (k >= 2) ? slot(k - 2) : slot(k - 1);  // unread when beta==0
        float alpha = (k == 1) ? 1.f : 2.f;
        float beta  = (k == 1) ? 0.f : -1.f;
        spmm_step_kernel<<<N_NODES, 64, 0, stream>>>(
            srcB, srcA, slot(k), row_ptr, cpack, alpha, beta);
        maybe_pass(k);
    }
}